// Round 1
// baseline (38.158 us; speedup 1.0000x reference)
//
#include <hip/hip_runtime.h>

// WaveletDomainLoss: mean |haar_dwt(pred) - haar_dwt(target)|
// Linear DWT => compute haar_dwt(pred - target) on the fly, L1-reduce.
// pred/target: (16, 6, 512, 512) fp32 contiguous. W = 512, rows of 512 floats.
// Unit = one float4 column-chunk spanning a row pair => 2 Haar 2x2 blocks.
// Total units = 25165824 / 8 = 3145728. Grid 2048x256 => 6 units/thread.

#define NBLOCKS 2048
#define NTHREADS 256
#define W 512
#define N_TOTAL 25165824L        // 16*6*512*512
#define N_UNITS (N_TOTAL / 8)    // 3145728

__global__ __launch_bounds__(NTHREADS) void haar_l1_partial(
    const float* __restrict__ pred,
    const float* __restrict__ tgt,
    float* __restrict__ ws)
{
    long tid = (long)blockIdx.x * NTHREADS + threadIdx.x;
    long stride = (long)gridDim.x * NTHREADS;
    float acc = 0.f;

    for (long u = tid; u < N_UNITS; u += stride) {
        long rp = u >> 7;            // row-pair index (128 float4 per row)
        long c4 = u & 127;           // float4 column
        long base = rp * (2L * W) + c4 * 4;

        float4 p0 = *(const float4*)(pred + base);
        float4 p1 = *(const float4*)(pred + base + W);
        float4 t0 = *(const float4*)(tgt + base);
        float4 t1 = *(const float4*)(tgt + base + W);

        float a, b, c, d;
        // block 0: cols {x,y}
        a = p0.x - t0.x; b = p0.y - t0.y; c = p1.x - t1.x; d = p1.y - t1.y;
        acc += fabsf(a + b + c + d) + fabsf(a + b - c - d)
             + fabsf(a - b + c - d) + fabsf(a - b - c + d);
        // block 1: cols {z,w}
        a = p0.z - t0.z; b = p0.w - t0.w; c = p1.z - t1.z; d = p1.w - t1.w;
        acc += fabsf(a + b + c + d) + fabsf(a + b - c - d)
             + fabsf(a - b + c - d) + fabsf(a - b - c + d);
    }

    // wave (64-lane) reduction
    #pragma unroll
    for (int off = 32; off > 0; off >>= 1)
        acc += __shfl_down(acc, off, 64);

    __shared__ float wsum[NTHREADS / 64];
    int wave = threadIdx.x >> 6;
    int lane = threadIdx.x & 63;
    if (lane == 0) wsum[wave] = acc;
    __syncthreads();
    if (threadIdx.x == 0)
        ws[blockIdx.x] = wsum[0] + wsum[1] + wsum[2] + wsum[3];
}

__global__ __launch_bounds__(NTHREADS) void haar_l1_final(
    const float* __restrict__ ws,
    float* __restrict__ out)
{
    float acc = 0.f;
    for (int i = threadIdx.x; i < NBLOCKS; i += NTHREADS)
        acc += ws[i];

    #pragma unroll
    for (int off = 32; off > 0; off >>= 1)
        acc += __shfl_down(acc, off, 64);

    __shared__ float wsum[NTHREADS / 64];
    int wave = threadIdx.x >> 6;
    int lane = threadIdx.x & 63;
    if (lane == 0) wsum[wave] = acc;
    __syncthreads();
    if (threadIdx.x == 0) {
        // coeff = 0.5*(±a±b±c±d); we summed without the 0.5. mean over N_TOTAL.
        const float scale = 0.5f / (float)N_TOTAL;
        out[0] = (wsum[0] + wsum[1] + wsum[2] + wsum[3]) * scale;
    }
}

extern "C" void kernel_launch(void* const* d_in, const int* in_sizes, int n_in,
                              void* d_out, int out_size, void* d_ws, size_t ws_size,
                              hipStream_t stream) {
    const float* pred = (const float*)d_in[0];
    const float* tgt  = (const float*)d_in[1];
    float* out = (float*)d_out;
    float* ws  = (float*)d_ws;   // needs NBLOCKS floats = 8 KiB

    haar_l1_partial<<<NBLOCKS, NTHREADS, 0, stream>>>(pred, tgt, ws);
    haar_l1_final<<<1, NTHREADS, 0, stream>>>(ws, out);
}